// Round 1
// baseline (153.342 us; speedup 1.0000x reference)
//
#include <hip/hip_runtime.h>
#include <stdint.h>

#define HH 224
#define WW 224
#define BB 4
#define PP 7          // seams per direction (NUM_SEG-1)
#define SEG 28        // W/8 == H/8
#define BW 5          // band_width
#define MM 11         // 2*BW+1
#define NITER 5

// ---------------------------------------------------------------------------
// Kernel 1: seam DP. One wave (64 threads) per (b, dir, p): 56 blocks.
// 11-state Viterbi over 224 steps, first-min tie rule, exact fp32 replication.
// ---------------------------------------------------------------------------
__global__ __launch_bounds__(64) void dp_kernel(const float* __restrict__ grad,
                                                int* __restrict__ coords_v,
                                                int* __restrict__ coords_h) {
    const int tid = threadIdx.x;     // 0..63
    int blk  = blockIdx.x;           // 0..55
    int p    = blk % PP;
    int rest = blk / PP;
    int dir  = rest & 1;             // 0 = vertical seams, 1 = horizontal
    int b    = rest >> 1;
    const float* g = grad + b * (HH * WW);
    const int base = SEG * (p + 1);

    __shared__ float    gseg[HH * MM];   // gseg[step][m]
    __shared__ unsigned pathw[HH];       // packed decisions: bits[0..10]=sel&1, bits[11..21]=sel>>1

    // --- stage A: gather the 11 columns/rows this seam needs into LDS ---
    if (dir == 0) {
        for (int i = tid; i < HH * MM; i += 64) {
            int y = i / MM, c = i - y * MM;
            int xc = base + c - BW; xc = min(max(xc, 0), WW - 1);
            gseg[i] = g[y * WW + xc];
        }
    } else {
        for (int i = tid; i < HH * MM; i += 64) {
            int c = i / WW, x = i - c * WW;     // x fastest -> coalesced row reads
            int yc = base + c - BW; yc = min(max(yc, 0), HH - 1);
            gseg[x * MM + c] = g[yc * WW + x];
        }
    }
    __syncthreads();

    // --- stage B: forward DP, state m held per-lane, neighbors via shfl ---
    const int mc   = min(tid, MM - 1);
    const int srcL = max(mc - 1, 0);
    const int srcR = min(mc + 1, MM - 1);
    float cost = -gseg[mc];                       // init = neg_g[0]
    for (int s = 1; s < HH; ++s) {
        float v1 = cost;
        float v0 = __shfl(cost, srcL);
        float v2 = __shfl(cost, srcR);
        // argmin-first over candidates [m-1(clip), m, m+1(clip)]
        bool a   = (v0 <= v1) && (v0 <= v2);
        bool m12 = (v1 <= v2);
        int   sel = a ? 0 : (m12 ? 1 : 2);
        float mv  = a ? v0 : (m12 ? v1 : v2);
        cost = mv - gseg[s * MM + mc];            // min_prev + (-g) == min_prev - g (IEEE)
        unsigned long long b0 = __ballot(sel & 1);
        unsigned long long b1 = __ballot(sel & 2);
        if (tid == 0)
            pathw[s] = (unsigned)(b0 & 0x7FFu) | ((unsigned)(b1 & 0x7FFu) << 11);
    }
    __syncthreads();

    // --- idx_last: first-min over the 11 final costs (all lanes compute) ---
    float best = __shfl(cost, 0); int idx = 0;
    for (int m = 1; m < MM; ++m) {
        float v = __shfl(cost, m);
        if (v < best) { best = v; idx = m; }
    }

    // --- backtrack (all lanes redundantly; lane 0 stores) ---
    int* cout = (dir == 0) ? coords_v : coords_h;
    int cur = idx;
    for (int s = HH - 1; s >= 1; --s) {
        if (tid == 0) {
            int col = min(max(base + cur - BW, 0), WW - 1);
            cout[(b * HH + s) * PP + p] = col;
        }
        unsigned wrd = pathw[s];
        int sel = (int)((wrd >> cur) & 1u) | (int)(((wrd >> (11 + cur)) & 1u) << 1);
        cur = min(max(cur + sel - 1, 0), MM - 1);
    }
    if (tid == 0) {
        int col = min(max(base + cur - BW, 0), WW - 1);
        cout[(b * HH + 0) * PP + p] = col;
    }
}

// ---------------------------------------------------------------------------
// Kernel 2: initial labels. seg = sum_p[cv<=x] + 8*sum_p[ch<=y]  (ranges per p
// are disjoint, so count == cumsum of the boolean mask).
// ---------------------------------------------------------------------------
__global__ __launch_bounds__(256) void label_kernel(const int* __restrict__ cv,
                                                    const int* __restrict__ ch,
                                                    unsigned char* __restrict__ labels) {
    int idx = blockIdx.x * 256 + threadIdx.x;
    if (idx >= BB * HH * WW) return;
    int b = idx / (HH * WW); int rem = idx - b * (HH * WW);
    int y = rem / WW; int x = rem - y * WW;
    const int* cvp = cv + (b * HH + y) * PP;   // coords of vertical seams in row y (x-coords)
    const int* chp = ch + (b * WW + x) * PP;   // coords of horizontal seams in col x (y-coords)
    int v = 0, h = 0;
#pragma unroll
    for (int q = 0; q < PP; ++q) { v += (cvp[q] <= x); h += (chp[q] <= y); }
    labels[idx] = (unsigned char)(v + 8 * h);
}

// ---------------------------------------------------------------------------
// Kernel 3: one voting iteration. Per-thread byte-packed 65-bin histogram in
// LDS, bank-aligned (lane t -> bank t%32). weight(d=chebyshev)=d<=1?3:4-d.
// Ties in argmax -> smallest k (ascending scan, strict >).
// ---------------------------------------------------------------------------
__global__ __launch_bounds__(256) void vote_kernel(const unsigned char* __restrict__ in,
                                                   unsigned char* __restrict__ out8,
                                                   int* __restrict__ out32) {
    __shared__ unsigned bins[17 * 256];   // bins[k>>2][t], byte k&3; word 16 = OOB sentinel
    const int tx = threadIdx.x, ty = threadIdx.y;
    const int t  = ty * 32 + tx;
    const int x  = blockIdx.x * 32 + tx;  // grid exact: 7*32=224
    const int y  = blockIdx.y * 8 + ty;   // 28*8=224
    const int b  = blockIdx.z;
    const unsigned char* img = in + b * (HH * WW);

#pragma unroll
    for (int c = 0; c < 17; ++c) bins[c * 256 + t] = 0u;
    // bins are thread-private: no barrier needed anywhere.

#pragma unroll
    for (int dy = -3; dy <= 3; ++dy) {
        int yy = y + dy;
        bool oky = (unsigned)yy < (unsigned)HH;
        int yc = min(max(yy, 0), HH - 1);
#pragma unroll
        for (int dx = -3; dx <= 3; ++dx) {
            int xx = x + dx;
            bool ok = oky && ((unsigned)xx < (unsigned)WW);
            int xc = min(max(xx, 0), WW - 1);
            int lab = img[yc * WW + xc];
            lab = ok ? lab : 64;                       // OOB -> sentinel bin
            const int ady = dy < 0 ? -dy : dy;
            const int adx = dx < 0 ? -dx : dx;
            const int d = ady > adx ? ady : adx;
            const unsigned w = (d <= 1) ? 3u : (unsigned)(4 - d);
            atomicAdd(&bins[(lab >> 2) * 256 + t], w << ((lab & 3) * 8));  // ds_add_u32, no RMW chain
        }
    }

    int best_s = -1, best_k = 0;
#pragma unroll
    for (int c = 0; c < 16; ++c) {
        unsigned wd = bins[c * 256 + t];
#pragma unroll
        for (int q = 0; q < 4; ++q) {
            int s = (int)((wd >> (q * 8)) & 255u);
            if (s > best_s) { best_s = s; best_k = c * 4 + q; }
        }
    }

    int o = b * (HH * WW) + y * WW + x;
    if (out8)  out8[o]  = (unsigned char)best_k;
    if (out32) out32[o] = best_k;
}

// ---------------------------------------------------------------------------
extern "C" void kernel_launch(void* const* d_in, const int* in_sizes, int n_in,
                              void* d_out, int out_size, void* d_ws, size_t ws_size,
                              hipStream_t stream) {
    const float* grad = (const float*)d_in[0];
    // band_width / num_iterations are fixed by setup_inputs (5 / 5) — compiled in.
    int* out = (int*)d_out;
    char* ws = (char*)d_ws;

    int* cv = (int*)(ws);                         // 4*224*7 int = 25088 B
    int* ch = (int*)(ws + 25088);                 // 25088 B
    unsigned char* laW = (unsigned char*)(ws + 50176);   // 200704 B (ws ping buffer)
    unsigned char* laD = (unsigned char*)d_out;          // pong buffer inside d_out (802816 B)

    dp_kernel<<<56, 64, 0, stream>>>(grad, cv, ch);
    label_kernel<<<(BB * HH * WW + 255) / 256, 256, 0, stream>>>(cv, ch, laW);

    dim3 grid(WW / 32, HH / 8, BB), blk(32, 8, 1);
    // 5 iterations: W->D, D->W, W->D, D->W, final W->int32(d_out)
    vote_kernel<<<grid, blk, 0, stream>>>(laW, laD, nullptr);
    vote_kernel<<<grid, blk, 0, stream>>>(laD, laW, nullptr);
    vote_kernel<<<grid, blk, 0, stream>>>(laW, laD, nullptr);
    vote_kernel<<<grid, blk, 0, stream>>>(laD, laW, nullptr);
    vote_kernel<<<grid, blk, 0, stream>>>(laW, nullptr, out);
}

// Round 2
// 142.310 us; speedup vs baseline: 1.0775x; 1.0775x over previous
//
#include <hip/hip_runtime.h>
#include <stdint.h>

#define HH 224
#define WW 224
#define BB 4
#define PP 7          // seams per direction
#define SEG 28
#define BW 5
#define MM 11         // 2*BW+1
#define GS 228        // padded per-(row,m) stride in gseg (mult of 4, %32==4)

#define POS_INF_I 0x7F800000
#define NEG_INF_F (-__builtin_huge_valf())

// map-compose for 11-entry 4-bit-nibble maps packed in u64:  H[i] = F[G[i]]
__device__ inline unsigned long long mcompose(unsigned long long F, unsigned long long G) {
    unsigned long long H = 0ull;
#pragma unroll
    for (int i = 0; i < 11; ++i) {
        unsigned g = (unsigned)(G >> (4 * i)) & 15u;
        unsigned long long h = (F >> (4 * g)) & 15ull;
        H |= h << (4 * i);
    }
    return H;
}

// ---------------------------------------------------------------------------
// DP kernel v2: 14 blocks x 64 threads; each 16-lane row runs one seam.
// Forward: DPP neighbor exchange (no LDS on critical path), ballot decisions.
// Backtrack: parallel suffix scan of decision maps.
// ---------------------------------------------------------------------------
__global__ __launch_bounds__(64) void dp_kernel(const float* __restrict__ grad,
                                                int* __restrict__ coords_v,
                                                int* __restrict__ coords_h) {
    __shared__ __align__(16) float gseg[4 * 16 * GS];  // [row][m(16)][s(GS)]
    __shared__ unsigned pathw[4 * 224];                // per (row, step) packed sel bits

    const int tid = threadIdx.x;
    const int l   = tid & 15;      // state lane (m = l for l<11)
    const int row = tid >> 4;      // seam-within-block
    const int sid = blockIdx.x * 4 + row;      // 0..55
    const int p   = sid % PP;
    const int dir = (sid / PP) & 1;
    const int b   = sid / (2 * PP);
    const int base = SEG * (p + 1);            // band center; base±5 never clips
    const float* gb = grad + b * (HH * WW);

    // ---- stage: lanes m=11..15 get -INF so their cost stays +INF forever ----
    for (int i = tid; i < 4 * 5 * GS; i += 64) {
        int r = i / (5 * GS);
        int rem = i - r * (5 * GS);
        int m = 11 + rem / GS;
        int s = rem - (m - 11) * GS;
        gseg[(r * 16 + m) * GS + s] = NEG_INF_F;
    }
    // ---- stage: the 11 band rows/cols for this row's seam ----
    if (dir == 0) {
        // vertical seam: gseg[row][m][s] = g[y=s][x=base-5+m]
        if (l < MM) {
            const float* src = gb + (base - BW + l);
#pragma unroll 4
            for (int s = 0; s < HH; ++s)
                gseg[(row * 16 + l) * GS + s] = src[s * WW];
        }
    } else {
        // horizontal seam: gseg[row][m][s] = g[y=base-5+m][x=s]
        for (int m = 0; m < MM; ++m) {
            const float* src = gb + (base - BW + m) * WW;
#pragma unroll
            for (int s0 = 0; s0 < HH; s0 += 16)
                gseg[(row * 16 + m) * GS + s0 + l] = src[s0 + l];
        }
    }
    __syncthreads();

    const float* gq = &gseg[(row * 16 + l) * GS];

    // ---- forward DP ----
#define DP_STEP(gval, s)                                                                     \
    {                                                                                        \
        float v1 = cost;                                                                     \
        float v0 = __int_as_float(__builtin_amdgcn_update_dpp(                               \
            POS_INF_I, __float_as_int(cost), 0x111, 0xf, 0xf, false)); /* row_shr:1 */       \
        float v2 = __int_as_float(__builtin_amdgcn_update_dpp(                               \
            POS_INF_I, __float_as_int(cost), 0x101, 0xf, 0xf, false)); /* row_shl:1 */       \
        bool a01 = (v0 <= v1), a02 = (v0 <= v2), a12 = (v1 <= v2);                           \
        unsigned long long A   = __ballot(a01 && a02);                                       \
        unsigned long long C12 = __ballot(a12);                                              \
        unsigned long long B0 = ~A & C12;  /* sel bit0 */                                    \
        unsigned long long B1 = ~A & ~C12; /* sel bit1 */                                    \
        float mv = (a01 && a02) ? v0 : (a12 ? v1 : v2);                                      \
        cost = mv - (gval);                                                                  \
        if (l == 0) {                                                                        \
            unsigned w = (unsigned)((B0 >> (row << 4)) & 0x7FFull) |                         \
                         ((unsigned)((B1 >> (row << 4)) & 0x7FFull) << 11);                  \
            pathw[row * 224 + (s)] = w;                                                      \
        }                                                                                    \
    }

    float4 cur = *(const float4*)&gq[0];
    float cost = -cur.x;                      // step 0 init: cost = neg_g[0]
    float4 nxt = *(const float4*)&gq[4];
    DP_STEP(cur.y, 1)
    DP_STEP(cur.z, 2)
    DP_STEP(cur.w, 3)
    for (int s0 = 4; s0 < 224; s0 += 4) {
        float4 c4 = nxt;
        int pf = s0 + 4;
        if (pf > 220) pf = 220;
        nxt = *(const float4*)&gq[pf];
        DP_STEP(c4.x, s0)
        DP_STEP(c4.y, s0 + 1)
        DP_STEP(c4.z, s0 + 2)
        DP_STEP(c4.w, s0 + 3)
    }
#undef DP_STEP

    // ---- idx_last: argmin-first across the 16-lane row ----
    float bc = cost;          // lanes 11..15 hold +INF
    int   bi = l;
#pragma unroll
    for (int mask = 1; mask < 16; mask <<= 1) {
        float oc = __shfl_xor(bc, mask, 16);
        int   oi = __shfl_xor(bi, mask, 16);
        if (oc < bc || (oc == bc && oi < bi)) { bc = oc; bi = oi; }
    }
    const int idx_last = bi;

    __syncthreads();   // pathw visible (same wave; cheap)

    // ---- backtrack: suffix scan of per-step maps ----
    // lane l owns map indices j in [14l+1, min(14l+14, 223)]
    const int lo = 14 * l + 1;
    const int hi_raw = 14 * l + 14;
    const int hi = hi_raw > 223 ? 223 : hi_raw;
    const int mcnt = hi - lo + 1;             // 14, except lane 15: 13

    unsigned w[14];
#pragma unroll
    for (int jj = 0; jj < 14; ++jj)
        w[jj] = (jj < mcnt) ? pathw[row * 224 + (lo + jj)] : 0u;

    // convert + compose local maps: L = map_lo o ... o map_hi (innermost = hi)
    const unsigned long long IDMAP = 0xA9876543210ull;  // i at nibble i
    unsigned long long L = IDMAP;
#pragma unroll
    for (int jj = 13; jj >= 0; --jj) {
        if (jj < mcnt) {
            unsigned ww = w[jj];
            unsigned long long M = 0ull;
#pragma unroll
            for (int i = 0; i < MM; ++i) {
                unsigned sel = ((ww >> i) & 1u) + 2u * ((ww >> (11 + i)) & 1u);
                unsigned long long prev = (unsigned long long)(i + (int)sel - 1); // in [0,10]
                M |= prev << (4 * i);
            }
            w[jj] = 0;           // reuse below? keep; we still need maps for emission
            // store compact map back into w? need u64; keep separate array:
            // (handled below by recomputing) -- instead stash M in a second array:
            // to keep registers bounded we recompute at emission; compose here:
            L = mcompose(M, L);
            w[jj] = ww;          // restore word for emission-phase recompute
        }
    }

    // inclusive suffix scan of L across the 16-lane row
    unsigned long long I = L;
#pragma unroll
    for (int d = 1; d < 16; d <<= 1) {
        unsigned long long O = __shfl_down(I, d, 16);
        if (l + d < 16) I = mcompose(I, O);
    }
    // exclusive suffix: R_l = I_{l+1} (identity for lane 15)
    unsigned long long R = __shfl_down(I, 1, 16);
    if (l == 15) R = IDMAP;

    int* cout = (dir == 0) ? coords_v : coords_h;
    // pos[223] = idx_last
    if (l == 15) cout[(b * HH + 223) * PP + p] = base + idx_last - BW;

    unsigned v = (unsigned)(R >> (4 * idx_last)) & 15u;
#pragma unroll
    for (int jj = 13; jj >= 0; --jj) {
        if (jj < mcnt) {
            unsigned ww = w[jj];
            unsigned sel = ((ww >> v) & 1u) + 2u * ((ww >> (11 + v)) & 1u);
            v = v + sel - 1u;                   // map_j applied
            int s = lo + jj - 1;                // emit pos[j-1]
            cout[(b * HH + s) * PP + p] = base + (int)v - BW;
        }
    }
}

// ---------------------------------------------------------------------------
// Kernel 2: initial labels (unchanged from passing version)
// ---------------------------------------------------------------------------
__global__ __launch_bounds__(256) void label_kernel(const int* __restrict__ cv,
                                                    const int* __restrict__ ch,
                                                    unsigned char* __restrict__ labels) {
    int idx = blockIdx.x * 256 + threadIdx.x;
    if (idx >= BB * HH * WW) return;
    int b = idx / (HH * WW); int rem = idx - b * (HH * WW);
    int y = rem / WW; int x = rem - y * WW;
    const int* cvp = cv + (b * HH + y) * PP;
    const int* chp = ch + (b * WW + x) * PP;
    int v = 0, h = 0;
#pragma unroll
    for (int q = 0; q < PP; ++q) { v += (cvp[q] <= x); h += (chp[q] <= y); }
    labels[idx] = (unsigned char)(v + 8 * h);
}

// ---------------------------------------------------------------------------
// Kernel 3: voting iteration (unchanged from passing version)
// ---------------------------------------------------------------------------
__global__ __launch_bounds__(256) void vote_kernel(const unsigned char* __restrict__ in,
                                                   unsigned char* __restrict__ out8,
                                                   int* __restrict__ out32) {
    __shared__ unsigned bins[17 * 256];
    const int tx = threadIdx.x, ty = threadIdx.y;
    const int t  = ty * 32 + tx;
    const int x  = blockIdx.x * 32 + tx;
    const int y  = blockIdx.y * 8 + ty;
    const int b  = blockIdx.z;
    const unsigned char* img = in + b * (HH * WW);

#pragma unroll
    for (int c = 0; c < 17; ++c) bins[c * 256 + t] = 0u;

#pragma unroll
    for (int dy = -3; dy <= 3; ++dy) {
        int yy = y + dy;
        bool oky = (unsigned)yy < (unsigned)HH;
        int yc = min(max(yy, 0), HH - 1);
#pragma unroll
        for (int dx = -3; dx <= 3; ++dx) {
            int xx = x + dx;
            bool ok = oky && ((unsigned)xx < (unsigned)WW);
            int xc = min(max(xx, 0), WW - 1);
            int lab = img[yc * WW + xc];
            lab = ok ? lab : 64;
            const int ady = dy < 0 ? -dy : dy;
            const int adx = dx < 0 ? -dx : dx;
            const int d = ady > adx ? ady : adx;
            const unsigned wgt = (d <= 1) ? 3u : (unsigned)(4 - d);
            atomicAdd(&bins[(lab >> 2) * 256 + t], wgt << ((lab & 3) * 8));
        }
    }

    int best_s = -1, best_k = 0;
#pragma unroll
    for (int c = 0; c < 16; ++c) {
        unsigned wd = bins[c * 256 + t];
#pragma unroll
        for (int q = 0; q < 4; ++q) {
            int s = (int)((wd >> (q * 8)) & 255u);
            if (s > best_s) { best_s = s; best_k = c * 4 + q; }
        }
    }

    int o = b * (HH * WW) + y * WW + x;
    if (out8)  out8[o]  = (unsigned char)best_k;
    if (out32) out32[o] = best_k;
}

// ---------------------------------------------------------------------------
extern "C" void kernel_launch(void* const* d_in, const int* in_sizes, int n_in,
                              void* d_out, int out_size, void* d_ws, size_t ws_size,
                              hipStream_t stream) {
    const float* grad = (const float*)d_in[0];
    int* out = (int*)d_out;
    char* ws = (char*)d_ws;

    int* cv = (int*)(ws);
    int* ch = (int*)(ws + 25088);
    unsigned char* laW = (unsigned char*)(ws + 50176);
    unsigned char* laD = (unsigned char*)d_out;

    dp_kernel<<<14, 64, 0, stream>>>(grad, cv, ch);
    label_kernel<<<(BB * HH * WW + 255) / 256, 256, 0, stream>>>(cv, ch, laW);

    dim3 grid(WW / 32, HH / 8, BB), blk(32, 8, 1);
    vote_kernel<<<grid, blk, 0, stream>>>(laW, laD, nullptr);
    vote_kernel<<<grid, blk, 0, stream>>>(laD, laW, nullptr);
    vote_kernel<<<grid, blk, 0, stream>>>(laW, laD, nullptr);
    vote_kernel<<<grid, blk, 0, stream>>>(laD, laW, nullptr);
    vote_kernel<<<grid, blk, 0, stream>>>(laW, nullptr, out);
}

// Round 4
// 128.012 us; speedup vs baseline: 1.1979x; 1.1117x over previous
//
#include <hip/hip_runtime.h>
#include <stdint.h>

#define HH 224
#define WW 224
#define BB 4
#define PP 7          // seams per direction
#define SEG 28
#define BW 5
#define MM 11         // 2*BW+1

#define POS_INF_I 0x7F800000

typedef const __attribute__((address_space(1))) unsigned int* gas_ptr;
typedef __attribute__((address_space(3))) unsigned int* las_ptr;

// map-compose for 11-entry 4-bit-nibble maps packed in u64:  H[i] = F[G[i]]
__device__ inline unsigned long long mcompose(unsigned long long F, unsigned long long G) {
    unsigned long long H = 0ull;
#pragma unroll
    for (int i = 0; i < 11; ++i) {
        unsigned g = (unsigned)(G >> (4 * i)) & 15u;
        H |= ((F >> (4 * g)) & 15ull) << (4 * i);
    }
    return H;
}

// ---------------------------------------------------------------------------
// DP kernel v3b: 56 blocks x 64 threads, one seam per block (dir uniform).
// Staging: async global_load_lds (56 issues, one drain). Forward: DPP neighbor
// exchange; wave-uniform decision words stored into the owning backtrack
// lane's registers via predicated select (wv is SGPR-resident -> v_cndmask).
// Backtrack: register maps + 16-lane suffix scan, no LDS.
// ---------------------------------------------------------------------------
__global__ __launch_bounds__(64) void dp_kernel(const float* __restrict__ grad,
                                                int* __restrict__ coords_v,
                                                int* __restrict__ coords_h) {
    __shared__ __align__(16) float gseg[225 * 16];   // [s][16]; row 224 = prefetch pad

    const int tid = threadIdx.x;
    const int l   = tid & 15;                  // DP state lane (m = l for l<11)
    const int sid = blockIdx.x;                // 0..55
    const int p   = sid % PP;
    const int dir = (sid / PP) & 1;            // block-uniform
    const int b   = sid / (2 * PP);
    const int base = SEG * (p + 1);            // band center; base-5..base+10 in-bounds
    const float* gb = grad + b * (HH * WW);

    // ---- async staging: chunk c covers steps 4c..4c+3; lane tid -> word c*64+tid ----
    {
        const int r  = tid >> 4;               // sub-step within chunk
        const int m  = tid & 15;
        const int sS = (dir == 0) ? WW : 1;    // step stride (elements)
        const int sM = (dir == 0) ? 1  : WW;   // band stride
        const float* src = gb + r * sS + (base - BW + m) * sM;
        const long stepBytes = (long)(4 * sS) * 4;   // 4 steps per chunk
#pragma unroll 8
        for (int c = 0; c < 56; ++c) {
            __builtin_amdgcn_global_load_lds((gas_ptr)(const void*)src,
                                             (las_ptr)(void*)(&gseg[c * 64]), 4, 0, 0);
            src = (const float*)((const char*)src + stepBytes);
        }
    }
    __syncthreads();   // drains vmcnt; orders gseg reads after async writes

    const float lane_add = (l < MM) ? 0.0f : __int_as_float(POS_INF_I);
    const float* gp = &gseg[l];

    unsigned wreg[16] = {};   // backtrack maps: lane t owns steps 16t+1..16t+16

#define DP_STEP(gval, ownb, jj_c)                                                       \
    {                                                                                   \
        float v1 = cost;                                                                \
        float v0 = __int_as_float(__builtin_amdgcn_update_dpp(                          \
            POS_INF_I, __float_as_int(cost), 0x111, 0xf, 0xf, false)); /* row_shr:1 */  \
        float v2 = __int_as_float(__builtin_amdgcn_update_dpp(                          \
            POS_INF_I, __float_as_int(cost), 0x101, 0xf, 0xf, false)); /* row_shl:1 */  \
        bool a01 = (v0 <= v1), a02 = (v0 <= v2), a12 = (v1 <= v2);                      \
        bool aa  = a01 && a02;                                                          \
        unsigned long long A   = __ballot(aa);                                          \
        unsigned long long C12 = __ballot(a12);                                         \
        unsigned long long B0 = ~A & C12;   /* sel bit0 */                              \
        unsigned long long B1 = ~A & ~C12;  /* sel bit1 */                              \
        float mv = aa ? v0 : (a12 ? v1 : v2);                                           \
        cost = mv - (gval) + lane_add;                                                  \
        unsigned wv = (unsigned)(B0 & 0x7FFull) | ((unsigned)(B1 & 0x7FFull) << 11);    \
        wreg[(jj_c)] = (ownb) ? wv : wreg[(jj_c)];  /* wv is SGPR -> v_cndmask */       \
    }

    // ---- forward DP: init + 223 steps = 13 full 16-groups + 15-step tail ----
    float cost = -gp[0] + lane_add;
    float buf[16], c0[16];
#pragma unroll
    for (int k = 0; k < 16; ++k) buf[k] = gp[(1 + k) * 16];
    for (int t = 0; t < 13; ++t) {
        const bool own = (tid == t);
#pragma unroll
        for (int k = 0; k < 16; ++k) c0[k] = buf[k];
#pragma unroll
        for (int k = 0; k < 16; ++k) buf[k] = gp[(16 * (t + 1) + 1 + k) * 16];
#pragma unroll
        for (int k = 0; k < 16; ++k) DP_STEP(c0[k], own, k)
    }
    {
        const bool own = (tid == 13);
#pragma unroll
        for (int k = 0; k < 15; ++k) DP_STEP(buf[k], own, k)   // steps 209..223
    }
#undef DP_STEP

    // ---- idx_last: argmin-first across the 16-lane group ----
    float bc = cost;                 // lanes 11..15 hold +INF
    int   bi = l;
#pragma unroll
    for (int mask = 1; mask < 16; mask <<= 1) {
        float oc = __shfl_xor(bc, mask, 16);
        int   oi = __shfl_xor(bi, mask, 16);
        if (oc < bc || (oc == bc && oi < bi)) { bc = oc; bi = oi; }
    }
    const int idx_last = bi;

    // ---- backtrack: compose per-lane maps, 16-lane suffix scan ----
    const int mcnt = (l < 13) ? 16 : ((l == 13) ? 15 : 0);
    const unsigned long long IDMAP = 0xA9876543210ull;
    unsigned long long L = IDMAP;
#pragma unroll
    for (int jj = 15; jj >= 0; --jj) {
        if (jj < mcnt) {
            unsigned ww = wreg[jj];
            unsigned long long M = 0ull;
#pragma unroll
            for (int i = 0; i < MM; ++i) {
                unsigned sel = ((ww >> i) & 1u) + 2u * ((ww >> (11 + i)) & 1u);
                M |= ((unsigned long long)(i + (int)sel - 1)) << (4 * i);
            }
            L = mcompose(M, L);
        }
    }
    unsigned long long I = L;
#pragma unroll
    for (int d = 1; d < 16; d <<= 1) {
        unsigned long long O = __shfl_down(I, d, 16);
        if (l + d < 16) I = mcompose(I, O);
    }
    unsigned long long R = __shfl_down(I, 1, 16);
    if (l == 15) R = IDMAP;

    int* cout = (dir == 0) ? coords_v : coords_h;
    if (tid == 15) cout[(b * HH + 223) * PP + p] = base + idx_last - BW;
    if (tid < 16) {
        unsigned v = (unsigned)(R >> (4 * idx_last)) & 15u;
#pragma unroll
        for (int jj = 15; jj >= 0; --jj) {
            if (jj < mcnt) {
                unsigned ww = wreg[jj];
                unsigned sel = ((ww >> v) & 1u) + 2u * ((ww >> (11 + v)) & 1u);
                v = v + sel - 1u;                 // pos[16l+jj]
                cout[(b * HH + (16 * l + jj)) * PP + p] = base + (int)v - BW;
            }
        }
    }
}

// ---------------------------------------------------------------------------
// Kernel 2: initial labels (unchanged — verified)
// ---------------------------------------------------------------------------
__global__ __launch_bounds__(256) void label_kernel(const int* __restrict__ cv,
                                                    const int* __restrict__ ch,
                                                    unsigned char* __restrict__ labels) {
    int idx = blockIdx.x * 256 + threadIdx.x;
    if (idx >= BB * HH * WW) return;
    int b = idx / (HH * WW); int rem = idx - b * (HH * WW);
    int y = rem / WW; int x = rem - y * WW;
    const int* cvp = cv + (b * HH + y) * PP;
    const int* chp = ch + (b * WW + x) * PP;
    int v = 0, h = 0;
#pragma unroll
    for (int q = 0; q < PP; ++q) { v += (cvp[q] <= x); h += (chp[q] <= y); }
    labels[idx] = (unsigned char)(v + 8 * h);
}

// ---------------------------------------------------------------------------
// Kernel 3: voting iteration (unchanged — verified)
// ---------------------------------------------------------------------------
__global__ __launch_bounds__(256) void vote_kernel(const unsigned char* __restrict__ in,
                                                   unsigned char* __restrict__ out8,
                                                   int* __restrict__ out32) {
    __shared__ unsigned bins[17 * 256];
    const int tx = threadIdx.x, ty = threadIdx.y;
    const int t  = ty * 32 + tx;
    const int x  = blockIdx.x * 32 + tx;
    const int y  = blockIdx.y * 8 + ty;
    const int b  = blockIdx.z;
    const unsigned char* img = in + b * (HH * WW);

#pragma unroll
    for (int c = 0; c < 17; ++c) bins[c * 256 + t] = 0u;

#pragma unroll
    for (int dy = -3; dy <= 3; ++dy) {
        int yy = y + dy;
        bool oky = (unsigned)yy < (unsigned)HH;
        int yc = min(max(yy, 0), HH - 1);
#pragma unroll
        for (int dx = -3; dx <= 3; ++dx) {
            int xx = x + dx;
            bool ok = oky && ((unsigned)xx < (unsigned)WW);
            int xc = min(max(xx, 0), WW - 1);
            int lab = img[yc * WW + xc];
            lab = ok ? lab : 64;
            const int ady = dy < 0 ? -dy : dy;
            const int adx = dx < 0 ? -dx : dx;
            const int d = ady > adx ? ady : adx;
            const unsigned wgt = (d <= 1) ? 3u : (unsigned)(4 - d);
            atomicAdd(&bins[(lab >> 2) * 256 + t], wgt << ((lab & 3) * 8));
        }
    }

    int best_s = -1, best_k = 0;
#pragma unroll
    for (int c = 0; c < 16; ++c) {
        unsigned wd = bins[c * 256 + t];
#pragma unroll
        for (int q = 0; q < 4; ++q) {
            int s = (int)((wd >> (q * 8)) & 255u);
            if (s > best_s) { best_s = s; best_k = c * 4 + q; }
        }
    }

    int o = b * (HH * WW) + y * WW + x;
    if (out8)  out8[o]  = (unsigned char)best_k;
    if (out32) out32[o] = best_k;
}

// ---------------------------------------------------------------------------
extern "C" void kernel_launch(void* const* d_in, const int* in_sizes, int n_in,
                              void* d_out, int out_size, void* d_ws, size_t ws_size,
                              hipStream_t stream) {
    const float* grad = (const float*)d_in[0];
    int* out = (int*)d_out;
    char* ws = (char*)d_ws;

    int* cv = (int*)(ws);
    int* ch = (int*)(ws + 25088);
    unsigned char* laW = (unsigned char*)(ws + 50176);
    unsigned char* laD = (unsigned char*)d_out;

    dp_kernel<<<56, 64, 0, stream>>>(grad, cv, ch);
    label_kernel<<<(BB * HH * WW + 255) / 256, 256, 0, stream>>>(cv, ch, laW);

    dim3 grid(WW / 32, HH / 8, BB), blk(32, 8, 1);
    vote_kernel<<<grid, blk, 0, stream>>>(laW, laD, nullptr);
    vote_kernel<<<grid, blk, 0, stream>>>(laD, laW, nullptr);
    vote_kernel<<<grid, blk, 0, stream>>>(laW, laD, nullptr);
    vote_kernel<<<grid, blk, 0, stream>>>(laD, laW, nullptr);
    vote_kernel<<<grid, blk, 0, stream>>>(laW, nullptr, out);
}